// Round 1
// baseline (242.639 us; speedup 1.0000x reference)
//
#include <hip/hip_runtime.h>
#include <math.h>

// Problem constants (from reference): x (B=4, T=4096, C=2048) fp32, kernel (K=4, C) fp32.
// y[b,t,c] = silu( sum_{j=0..3} k[j,c] * x[b,t-j,c] ), x zero-padded for t-j<0.
// next_cache = x[:, T-3:, :]  (B*3*C floats, appended flat after y in d_out).

#define B_   4
#define T_   4096
#define C_   2048
#define K_   4
#define C4_  (C_ / 4)   // 512 float4 groups per row
#define TT_  32         // timesteps per block (sliding window)

__global__ __launch_bounds__(C4_) void dwconv_silu_kernel(
    const float4* __restrict__ x,      // [B, T, C4] as float4
    const float4* __restrict__ kern,   // [K, C4] as float4
    float4* __restrict__ y)            // [B, T, C4] as float4
{
    const int c4 = threadIdx.x;        // 0..511, owns channels 4*c4..4*c4+3
    const int b  = blockIdx.y;
    const int t0 = blockIdx.x * TT_;

    // Per-thread kernel weights (4 channels x 4 taps)
    const float4 k0 = kern[0 * C4_ + c4];
    const float4 k1 = kern[1 * C4_ + c4];
    const float4 k2 = kern[2 * C4_ + c4];
    const float4 k3 = kern[3 * C4_ + c4];

    const float4* xb = x + (size_t)b * T_ * C4_;
    float4*       yb = y + (size_t)b * T_ * C4_;

    // Sliding window: xm1 = x[t-1], xm2 = x[t-2], xm3 = x[t-3]
    float4 xm1, xm2, xm3;
    if (t0 == 0) {
        xm1 = make_float4(0.f, 0.f, 0.f, 0.f);
        xm2 = xm1;
        xm3 = xm1;
    } else {
        xm1 = xb[(size_t)(t0 - 1) * C4_ + c4];
        xm2 = xb[(size_t)(t0 - 2) * C4_ + c4];
        xm3 = xb[(size_t)(t0 - 3) * C4_ + c4];
    }

    #pragma unroll 4
    for (int i = 0; i < TT_; ++i) {
        const int t = t0 + i;
        const float4 x0 = xb[(size_t)t * C4_ + c4];

        float4 r;
        r.x = fmaf(k0.x, x0.x, fmaf(k1.x, xm1.x, fmaf(k2.x, xm2.x, k3.x * xm3.x)));
        r.y = fmaf(k0.y, x0.y, fmaf(k1.y, xm1.y, fmaf(k2.y, xm2.y, k3.y * xm3.y)));
        r.z = fmaf(k0.z, x0.z, fmaf(k1.z, xm1.z, fmaf(k2.z, xm2.z, k3.z * xm3.z)));
        r.w = fmaf(k0.w, x0.w, fmaf(k1.w, xm1.w, fmaf(k2.w, xm2.w, k3.w * xm3.w)));

        // SiLU: v / (1 + exp(-v)).  (exp(-v) -> inf for large -v gives 0 cleanly)
        r.x = r.x / (1.f + expf(-r.x));
        r.y = r.y / (1.f + expf(-r.y));
        r.z = r.z / (1.f + expf(-r.z));
        r.w = r.w / (1.f + expf(-r.w));

        yb[(size_t)t * C4_ + c4] = r;

        xm3 = xm2;
        xm2 = xm1;
        xm1 = x0;
    }
}

// next_cache = x[:, T-3:, :]  -> d_out + B*T*C, size B*3*C floats = 6144 float4
__global__ __launch_bounds__(256) void cache_copy_kernel(
    const float4* __restrict__ x, float4* __restrict__ cache)
{
    const int i = blockIdx.x * blockDim.x + threadIdx.x;  // 0 .. B*3*C4-1
    if (i >= B_ * (K_ - 1) * C4_) return;
    const int b  = i / ((K_ - 1) * C4_);
    const int rc = i % ((K_ - 1) * C4_);
    const int t  = T_ - (K_ - 1) + rc / C4_;
    const int c4 = rc % C4_;
    cache[i] = x[((size_t)b * T_ + t) * C4_ + c4];
}

extern "C" void kernel_launch(void* const* d_in, const int* in_sizes, int n_in,
                              void* d_out, int out_size, void* d_ws, size_t ws_size,
                              hipStream_t stream)
{
    const float4* x    = (const float4*)d_in[0];
    const float4* kern = (const float4*)d_in[1];
    float*        out  = (float*)d_out;

    float4* y     = (float4*)out;                                // B*T*C floats
    float4* cache = (float4*)(out + (size_t)B_ * T_ * C_);       // B*3*C floats

    dim3 grid(T_ / TT_, B_);   // (128, 4)
    dim3 block(C4_);           // 512
    dwconv_silu_kernel<<<grid, block, 0, stream>>>(x, kern, y);

    const int cache_elems4 = B_ * (K_ - 1) * C4_;  // 6144
    cache_copy_kernel<<<(cache_elems4 + 255) / 256, 256, 0, stream>>>(x, cache);
}

// Round 3
// 238.672 us; speedup vs baseline: 1.0166x; 1.0166x over previous
//
#include <hip/hip_runtime.h>
#include <math.h>

// Causal depthwise conv1d K=4 + SiLU. x (B=4, T=4096, C=2048) fp32, kernel (4, C) fp32.
// y[b,t,c] = silu( sum_j k[j,c] * x[b,t-j,c] ), zero-padded; next_cache = x[:, T-3:, :].
//
// R1 analysis: 86us kernel, Occupancy 37.8%, BW ~3.1 TB/s (latency-bound, not BW-bound).
// Fix: TT=16 -> 1024 blocks = 4 blocks/CU = 32 waves/CU; batch-of-4 prefetch for 4
// outstanding loads/thread; launch_bounds(512,8) pins VGPR<=64 so 8 waves/SIMD fit.
// R2: __builtin_nontemporal_store needs a real vector type, not HIP's float4 class
//     -> store via ext_vector_type alias.

#define B_   4
#define T_   4096
#define C_   2048
#define K_   4
#define C4_  (C_ / 4)   // 512 float4 groups per row
#define TT_  16         // timesteps per block

typedef float nat_float4 __attribute__((ext_vector_type(4)));

__device__ __forceinline__ float silu_f(float v) {
    return v * __frcp_rn(1.f + __expf(-v));
}

__device__ __forceinline__ void store_nt(float4* p, const float4& v) {
    nat_float4 nv = { v.x, v.y, v.z, v.w };
    __builtin_nontemporal_store(nv, reinterpret_cast<nat_float4*>(p));
}

__global__ __launch_bounds__(C4_, 8) void dwconv_silu_kernel(
    const float4* __restrict__ x,      // [B, T, C4]
    const float4* __restrict__ kern,   // [K, C4]
    float4* __restrict__ y)            // [B, T, C4]
{
    const int c4 = threadIdx.x;        // 0..511
    const int b  = blockIdx.y;
    const int t0 = blockIdx.x * TT_;

    const float4 k0 = kern[0 * C4_ + c4];
    const float4 k1 = kern[1 * C4_ + c4];
    const float4 k2 = kern[2 * C4_ + c4];
    const float4 k3 = kern[3 * C4_ + c4];

    const float4* xb = x + (size_t)b * T_ * C4_ + c4;
    float4*       yb = y + (size_t)b * T_ * C4_ + c4;

    // Sliding window registers: xm1 = x[t-1], xm2 = x[t-2], xm3 = x[t-3]
    float4 xm1, xm2, xm3;
    if (t0 == 0) {
        xm1 = make_float4(0.f, 0.f, 0.f, 0.f);
        xm2 = xm1;
        xm3 = xm1;
    } else {
        xm1 = xb[(size_t)(t0 - 1) * C4_];
        xm2 = xb[(size_t)(t0 - 2) * C4_];
        xm3 = xb[(size_t)(t0 - 3) * C4_];
    }

#define CONV1(r, a, w1, w2, w3)                                              \
    r.x = fmaf(k0.x, a.x, fmaf(k1.x, w1.x, fmaf(k2.x, w2.x, k3.x * w3.x)));  \
    r.y = fmaf(k0.y, a.y, fmaf(k1.y, w1.y, fmaf(k2.y, w2.y, k3.y * w3.y)));  \
    r.z = fmaf(k0.z, a.z, fmaf(k1.z, w1.z, fmaf(k2.z, w2.z, k3.z * w3.z)));  \
    r.w = fmaf(k0.w, a.w, fmaf(k1.w, w1.w, fmaf(k2.w, w2.w, k3.w * w3.w)));  \
    r.x = silu_f(r.x); r.y = silu_f(r.y); r.z = silu_f(r.z); r.w = silu_f(r.w);

    #pragma unroll
    for (int i = 0; i < TT_; i += 4) {
        // 4 independent loads in flight
        const float4 a0 = xb[(size_t)(t0 + i + 0) * C4_];
        const float4 a1 = xb[(size_t)(t0 + i + 1) * C4_];
        const float4 a2 = xb[(size_t)(t0 + i + 2) * C4_];
        const float4 a3 = xb[(size_t)(t0 + i + 3) * C4_];

        float4 r0, r1, r2, r3;
        CONV1(r0, a0, xm1, xm2, xm3)
        CONV1(r1, a1, a0,  xm1, xm2)
        CONV1(r2, a2, a1,  a0,  xm1)
        CONV1(r3, a3, a2,  a1,  a0)

        // y is write-once: non-temporal stores keep L2 for x halo reuse
        store_nt(&yb[(size_t)(t0 + i + 0) * C4_], r0);
        store_nt(&yb[(size_t)(t0 + i + 1) * C4_], r1);
        store_nt(&yb[(size_t)(t0 + i + 2) * C4_], r2);
        store_nt(&yb[(size_t)(t0 + i + 3) * C4_], r3);

        xm3 = a1;
        xm2 = a2;
        xm1 = a3;
    }
#undef CONV1
}

// next_cache = x[:, T-3:, :]  -> d_out + B*T*C  (B*3*C floats = 6144 float4)
__global__ __launch_bounds__(256) void cache_copy_kernel(
    const float4* __restrict__ x, float4* __restrict__ cache)
{
    const int i = blockIdx.x * blockDim.x + threadIdx.x;
    if (i >= B_ * (K_ - 1) * C4_) return;
    const int b  = i / ((K_ - 1) * C4_);
    const int rc = i % ((K_ - 1) * C4_);
    const int t  = T_ - (K_ - 1) + rc / C4_;
    const int c4 = rc % C4_;
    cache[i] = x[((size_t)b * T_ + t) * C4_ + c4];
}

extern "C" void kernel_launch(void* const* d_in, const int* in_sizes, int n_in,
                              void* d_out, int out_size, void* d_ws, size_t ws_size,
                              hipStream_t stream)
{
    const float4* x    = (const float4*)d_in[0];
    const float4* kern = (const float4*)d_in[1];
    float*        out  = (float*)d_out;

    float4* y     = (float4*)out;
    float4* cache = (float4*)(out + (size_t)B_ * T_ * C_);

    dim3 grid(T_ / TT_, B_);   // (256, 4) = 1024 blocks -> 4 blocks/CU
    dim3 block(C4_);           // 512 threads
    dwconv_silu_kernel<<<grid, block, 0, stream>>>(x, kern, y);

    const int cache_elems4 = B_ * (K_ - 1) * C4_;  // 6144
    cache_copy_kernel<<<(cache_elems4 + 255) / 256, 256, 0, stream>>>(x, cache);
}